// Round 5
// baseline (1133.070 us; speedup 1.0000x reference)
//
#include <hip/hip_runtime.h>
#include <cstdint>

// out[b,s,o] = sum_k in[b,s,k] * lut[w[o,k]] + bias[o]
// GEMM: M=8192, N=4096, K=4096, fp32 out, f16 MFMA path.
//
// R8: R7 (verified: 242us gemm, MfmaUtil 52.5%, 0 conflicts, no spill) +
// early-barrier boundary: vmcnt(0)+s_barrier moves to right after PH1's
// LGKM(0) (all my buf-cur reads drained + my stage loads confirmed), so the
// 12-read entry burst for the next buffer + stage(kt+2) issue BEFORE the
// PH2+PH3 back-to-back MFMA block (620cy/SIMD) instead of before PH3 only
// (310cy). Theory: R7's ~1700cy/tile stall is the 96-read entry burst
// (1150cy of CU LDS pipe) outrunning its MFMA cover.
//  - also fused cvt_a+dequant_b into one `prep` dispatch (launch saving +
//    diagnosis: its duration-by-name tells whether the 255us non-gemm gap
//    is really in these kernels).
// Predicted: gemm ~195-210us, MfmaUtil ~60-66%, total ~440-460us.

static constexpr int Md = 8192;
static constexpr int Nd = 4096;
static constexpr int Kd = 4096;
static constexpr int NKT = Kd / 64;

typedef _Float16 half8 __attribute__((ext_vector_type(8)));
typedef float f32x4 __attribute__((ext_vector_type(4)));

__device__ __forceinline__ void async_copy16(const _Float16* g, _Float16* l) {
  __builtin_amdgcn_global_load_lds((const __attribute__((address_space(1))) void*)g,
                                   (__attribute__((address_space(3))) void*)l, 16, 0, 0);
}

#define LGKM(n) asm volatile("s_waitcnt lgkmcnt(" #n ")" ::: "memory")
#define VMCNT(n) asm volatile("s_waitcnt vmcnt(" #n ")" ::: "memory")
#define BAR() __builtin_amdgcn_s_barrier()
#define SB0() __builtin_amdgcn_sched_barrier(0)

// ds_read_b128 with literal offset; asm keeps hipcc from inserting vmcnt(0)
// RAW drains against global_load_lds (R5-verified win).
#define R16(dst, base, OFF) \
  asm volatile("ds_read_b128 %0, %1 offset:" #OFF : "=v"(dst) : "v"(base))

// ---- fused pre-pass: blocks [0,16384) convert A fp32->fp16; blocks
// [16384,24576) dequant W idx->fp16 via LDS LUT. Block-uniform branch.
__global__ __launch_bounds__(256) void prep(const float* __restrict__ in,
                                            _Float16* __restrict__ Ah,
                                            const int* __restrict__ w,
                                            const float* __restrict__ lut,
                                            _Float16* __restrict__ Bh) {
  __shared__ float slut[256];
  const int bx = blockIdx.x;
  if (bx < 16384) {
    const size_t i = (size_t)bx * 256 + threadIdx.x;
    const float4 x = ((const float4*)in)[2 * i];
    const float4 y = ((const float4*)in)[2 * i + 1];
    half8 h;
    h[0] = (_Float16)x.x; h[1] = (_Float16)x.y; h[2] = (_Float16)x.z; h[3] = (_Float16)x.w;
    h[4] = (_Float16)y.x; h[5] = (_Float16)y.y; h[6] = (_Float16)y.z; h[7] = (_Float16)y.w;
    *(half8*)(Ah + 8 * i) = h;
  } else {
    slut[threadIdx.x] = lut[threadIdx.x];
    __syncthreads();
    const size_t i = (size_t)(bx - 16384) * 256 + threadIdx.x;
    const int4 a = ((const int4*)w)[2 * i];
    const int4 b = ((const int4*)w)[2 * i + 1];
    half8 h;
    h[0] = (_Float16)slut[a.x]; h[1] = (_Float16)slut[a.y];
    h[2] = (_Float16)slut[a.z]; h[3] = (_Float16)slut[a.w];
    h[4] = (_Float16)slut[b.x]; h[5] = (_Float16)slut[b.y];
    h[6] = (_Float16)slut[b.z]; h[7] = (_Float16)slut[b.w];
    *(half8*)(Bh + 8 * i) = h;
  }
}

// ---- C[M][N] = A[M][K] * Bt[N][K]^T + bias ----
// 256x256 tile, BK=64, 8 waves (2Mx4N), per-wave 128x64 out, acc[8][4] f32x4.
__global__ __launch_bounds__(512, 1) void gemm_f16(const _Float16* __restrict__ A,
                                                   const _Float16* __restrict__ Bt,
                                                   const float* __restrict__ bias,
                                                   float* __restrict__ C) {
  __shared__ __align__(16) _Float16 As[2][256 * 64];
  __shared__ __align__(16) _Float16 Bs[2][256 * 64];

  const int tid = threadIdx.x;
  const int lane = tid & 63;
  const int wave = tid >> 6;
  const int wm = wave >> 2;  // 0..1
  const int wn = wave & 3;   // 0..3

  // XCD swizzle: 512 blocks -> 8 chunks of 64 consecutive per XCD.
  const int bid0 = blockIdx.x + blockIdx.y * gridDim.x;  // grid (32,16)
  const int bid = (bid0 & 7) * 64 + (bid0 >> 3);
  const int bm = bid & 31;
  const int bn = bid >> 5;

  // ---- staging: 512 thr x 16B = 64 rows/issuance, 4 per half op.
  // LDS dest linear; swizzle on GLOBAL source chunk: slot (tid&7) gets
  // global chunk (tid&7)^(row&7).
  const int trow = tid >> 3;
  const int tcol = tid & 7;
  const int gch = tcol ^ (trow & 7);
  const _Float16* ag = A + (size_t)(bm * 256 + trow) * Kd + gch * 8;
  const _Float16* bg = Bt + (size_t)(bn * 256 + trow) * Kd + gch * 8;
  const int lds_off = trow * 64 + tcol * 8;

  auto stage = [&](int buf, int kt) {
#pragma unroll
    for (int ht = 0; ht < 4; ++ht) {
      async_copy16(ag + (size_t)kt * 64 + (size_t)ht * (64 * Kd),
                   &As[buf][lds_off + ht * 4096]);
      async_copy16(bg + (size_t)kt * 64 + (size_t)ht * (64 * Kd),
                   &Bs[buf][lds_off + ht * 4096]);
    }
  };

  // ---- fragment addressing: chunk c of row r sits at slot c^(r&7); row=128B.
  // 16x16x32: fr=lane&15 row, fq=lane>>4 selects k-chunk (fq / 4|fq).
  const int fr = lane & 15;
  const int fq = lane >> 4;
  const int e = fr & 7;
  const uint32_t aS0 = (uint32_t)(uintptr_t)&As[0][0] +
                       (uint32_t)((wm * 128 + fr) * 128) + (uint32_t)((fq ^ e) * 16);
  const uint32_t aS1 = (uint32_t)(uintptr_t)&As[0][0] +
                       (uint32_t)((wm * 128 + fr) * 128) + (uint32_t)((((4 | fq) ^ e)) * 16);
  const uint32_t bS0 = (uint32_t)(uintptr_t)&Bs[0][0] +
                       (uint32_t)((wn * 64 + fr) * 128) + (uint32_t)((fq ^ e) * 16);
  const uint32_t bS1 = (uint32_t)(uintptr_t)&Bs[0][0] +
                       (uint32_t)((wn * 64 + fr) * 128) + (uint32_t)((((4 | fq) ^ e)) * 16);
  // buf1 = +32768 bytes, folded into the ds_read offset immediates.

  half8 aL[4][2], aH[4][2], b0A[2][2], b0B[2][2], b1[2][2];
  f32x4 acc[8][4] = {};

  // 12-read entry set (aL + b0) for each buffer/parity:
#define R_ENTRY_B0()                                             \
  R16(aL[0][0], aS0, 0);     R16(aL[0][1], aS1, 0);              \
  R16(aL[1][0], aS0, 2048);  R16(aL[1][1], aS1, 2048);           \
  R16(aL[2][0], aS0, 4096);  R16(aL[2][1], aS1, 4096);           \
  R16(aL[3][0], aS0, 6144);  R16(aL[3][1], aS1, 6144);           \
  R16(b0A[0][0], bS0, 0);    R16(b0A[0][1], bS1, 0);             \
  R16(b0A[1][0], bS0, 2048); R16(b0A[1][1], bS1, 2048)

#define R_ENTRY_B1()                                             \
  R16(aL[0][0], aS0, 32768); R16(aL[0][1], aS1, 32768);          \
  R16(aL[1][0], aS0, 34816); R16(aL[1][1], aS1, 34816);          \
  R16(aL[2][0], aS0, 36864); R16(aL[2][1], aS1, 36864);          \
  R16(aL[3][0], aS0, 38912); R16(aL[3][1], aS1, 38912);          \
  R16(b0B[0][0], bS0, 32768); R16(b0B[0][1], bS1, 32768);        \
  R16(b0B[1][0], bS0, 34816); R16(b0B[1][1], bS1, 34816)

#define R_B1_0()                                                 \
  R16(b1[0][0], bS0, 4096);  R16(b1[0][1], bS1, 4096);           \
  R16(b1[1][0], bS0, 6144);  R16(b1[1][1], bS1, 6144)

#define R_B1_1()                                                 \
  R16(b1[0][0], bS0, 36864); R16(b1[0][1], bS1, 36864);          \
  R16(b1[1][0], bS0, 38912); R16(b1[1][1], bS1, 38912)

#define R_AH_0()                                                 \
  R16(aH[0][0], aS0, 8192);  R16(aH[0][1], aS1, 8192);           \
  R16(aH[1][0], aS0, 10240); R16(aH[1][1], aS1, 10240);          \
  R16(aH[2][0], aS0, 12288); R16(aH[2][1], aS1, 12288);          \
  R16(aH[3][0], aS0, 14336); R16(aH[3][1], aS1, 14336)

#define R_AH_1()                                                 \
  R16(aH[0][0], aS0, 40960); R16(aH[0][1], aS1, 40960);          \
  R16(aH[1][0], aS0, 43008); R16(aH[1][1], aS1, 43008);          \
  R16(aH[2][0], aS0, 45056); R16(aH[2][1], aS1, 45056);          \
  R16(aH[3][0], aS0, 47104); R16(aH[3][1], aS1, 47104)

#define MF(d, x, y) d = __builtin_amdgcn_mfma_f32_16x16x32_f16(x, y, d, 0, 0, 0)

#define PH0(B0)                                          \
  _Pragma("unroll") for (int i = 0; i < 4; ++i)          \
  _Pragma("unroll") for (int j = 0; j < 2; ++j) {        \
    MF(acc[i][j], aL[i][0], B0[j][0]);                   \
    MF(acc[i][j], aL[i][1], B0[j][1]);                   \
  }
#define PH1()                                            \
  _Pragma("unroll") for (int i = 0; i < 4; ++i)          \
  _Pragma("unroll") for (int j = 0; j < 2; ++j) {        \
    MF(acc[i][2 + j], aL[i][0], b1[j][0]);               \
    MF(acc[i][2 + j], aL[i][1], b1[j][1]);               \
  }
#define PH2()                                            \
  _Pragma("unroll") for (int i = 0; i < 4; ++i)          \
  _Pragma("unroll") for (int j = 0; j < 2; ++j) {        \
    MF(acc[4 + i][2 + j], aH[i][0], b1[j][0]);           \
    MF(acc[4 + i][2 + j], aH[i][1], b1[j][1]);           \
  }
#define PH3(B0)                                          \
  _Pragma("unroll") for (int i = 0; i < 4; ++i)          \
  _Pragma("unroll") for (int j = 0; j < 2; ++j) {        \
    MF(acc[4 + i][j], aH[i][0], B0[j][0]);               \
    MF(acc[4 + i][j], aH[i][1], B0[j][1]);               \
  }

#define PRIO1() __builtin_amdgcn_s_setprio(1)
#define PRIO0() __builtin_amdgcn_s_setprio(0)

  // prologue: stage tiles 0,1; wait own tile-0 loads; barrier; entry reads.
  stage(0, 0);
  stage(1, 1);
  VMCNT(8);
  BAR();
  R_ENTRY_B0();

  for (int kt = 0; kt < NKT; kt += 2) {
    // ================= even tile kt (buf0, parity A) =================
    R_B1_0();                                    // 4 reads; outstanding 12+4
    LGKM(4); SB0(); PRIO1(); PH0(b0A); PRIO0();  // entry reads drained
    R_AH_0();                                    // 8 reads; outstanding 4+8
    LGKM(8); SB0(); PRIO1(); PH1(); PRIO0();     // b1 drained
    LGKM(0);   // aH drained -> all my buf0 reads complete
    VMCNT(0);  // my stage(buf1,kt+1) loads (issued one tile ago) complete
    BAR();     // ALL waves: buf0 read-done + buf1 staged
    R_ENTRY_B1();                                // 12 reads for tile kt+1
    if (kt + 2 < NKT) stage(0, kt + 2);          // overwrite buf0 (safe)
    SB0(); PRIO1(); PH2(); PH3(b0A); PRIO0();    // 32 MFMA cover the burst

    // ================= odd tile kt+1 (buf1, parity B) ================
    R_B1_1();
    LGKM(4); SB0(); PRIO1(); PH0(b0B); PRIO0();
    R_AH_1();
    LGKM(8); SB0(); PRIO1(); PH1(); PRIO0();
    LGKM(0);
    if (kt + 2 < NKT) {
      VMCNT(0);  // my stage(buf0,kt+2) loads (issued ~2.5 phases ago)
      BAR();
      R_ENTRY_B0();                              // 12 reads for tile kt+2
      if (kt + 3 < NKT) stage(1, kt + 3);
      SB0(); PRIO1(); PH2(); PH3(b0B); PRIO0();
    } else {
      SB0(); PRIO1(); PH2(); PH3(b0B); PRIO0();
    }
  }

  // ---- epilogue: C/D layout col = lane&15, row = (lane>>4)*4 + reg
  const int ccol0 = bn * 256 + wn * 64 + fr;
  const int crow0 = bm * 256 + wm * 128 + fq * 4;
  float bv[4];
#pragma unroll
  for (int j = 0; j < 4; ++j) bv[j] = bias[ccol0 + j * 16];
#pragma unroll
  for (int i = 0; i < 8; ++i) {
#pragma unroll
    for (int r = 0; r < 4; ++r) {
      float* cp = C + (size_t)(crow0 + i * 16 + r) * Nd + ccol0;
#pragma unroll
      for (int j = 0; j < 4; ++j) cp[j * 16] = acc[i][j][r] + bv[j];
    }
  }
}

extern "C" void kernel_launch(void* const* d_in, const int* in_sizes, int n_in,
                              void* d_out, int out_size, void* d_ws, size_t ws_size,
                              hipStream_t stream) {
  const float* inp = (const float*)d_in[0];
  const float* lut = (const float*)d_in[1];
  const int* wgt = (const int*)d_in[2];
  const float* bias = (const float*)d_in[3];
  float* out = (float*)d_out;

  _Float16* Ah = (_Float16*)d_ws;
  _Float16* Bh = (_Float16*)d_ws + (size_t)Md * Kd;

  // fused pre-pass: 16384 cvt blocks + 8192 dequant blocks
  prep<<<24576, 256, 0, stream>>>(inp, Ah, wgt, lut, Bh);

  dim3 grid(Md / 256, Nd / 256);  // (32, 16) = 512 blocks
  gemm_f16<<<grid, 512, 0, stream>>>(Ah, Bh, bias, out);
}

// Round 6
// 695.557 us; speedup vs baseline: 1.6290x; 1.6290x over previous
//
#include <hip/hip_runtime.h>
#include <cstdint>

// out[b,s,o] = sum_k in[b,s,k] * lut[w[o,k]] + bias[o]
// GEMM: M=8192, N=4096, K=4096, fp32 out, f16 MFMA path.
//
// R9: recover R7 (242us gemm verified; R8's early-barrier variant spilled:
// peak-simultaneous-live 112 operand VGPRs + 128 acc = over the 256/wave
// unified cap at 8 waves/CU -> 2GB scratch WRITE_SIZE) with register-safe
// changes only:
//  - quadrant order P00(aL,b0) P01(aL,b1) P10(aH,b0) | boundary | P11(aH,b1):
//    b0 dies at P10 -> entry reads reuse aL/b0 regs, NO parity set (-16 VGPR
//    allocated; peak-live unchanged ~238 incl. acc).
//  - boundary convoy smoothing: after the barrier, issue 8 aL-reads, run 8
//    MFMA (P11a), issue 4 b0-reads, run 8 MFMA (P11b); the 8 global_load_lds
//    stage issues move AFTER P11 (they have a full tile of slack and don't
//    belong in the post-barrier LDS-queue window).
//  - counted lgkm per phase (reads issued one phase ahead), one barrier/tile,
//    vmcnt never 0 mid-pipeline except the boundary drain of tile-old loads.
// Predicted: gemm ~215-235us, MfmaUtil 53-58%, WRITE ~135MB, VGPR ~112-120.

static constexpr int Md = 8192;
static constexpr int Nd = 4096;
static constexpr int Kd = 4096;
static constexpr int NKT = Kd / 64;

typedef _Float16 half8 __attribute__((ext_vector_type(8)));
typedef float f32x4 __attribute__((ext_vector_type(4)));

__device__ __forceinline__ void async_copy16(const _Float16* g, _Float16* l) {
  __builtin_amdgcn_global_load_lds((const __attribute__((address_space(1))) void*)g,
                                   (__attribute__((address_space(3))) void*)l, 16, 0, 0);
}

#define LGKM(n) asm volatile("s_waitcnt lgkmcnt(" #n ")" ::: "memory")
#define VMCNT(n) asm volatile("s_waitcnt vmcnt(" #n ")" ::: "memory")
#define BAR() __builtin_amdgcn_s_barrier()
#define SB0() __builtin_amdgcn_sched_barrier(0)
#define PRIO1() __builtin_amdgcn_s_setprio(1)
#define PRIO0() __builtin_amdgcn_s_setprio(0)

// ds_read_b128 with literal offset; asm keeps hipcc from inserting vmcnt(0)
// RAW drains against global_load_lds (R5-verified win).
#define R16(dst, base, OFF) \
  asm volatile("ds_read_b128 %0, %1 offset:" #OFF : "=v"(dst) : "v"(base))

// ---- fused pre-pass: blocks [0,16384) convert A fp32->fp16; blocks
// [16384,24576) dequant W idx->fp16 via LDS LUT. Block-uniform branch.
__global__ __launch_bounds__(256) void prep(const float* __restrict__ in,
                                            _Float16* __restrict__ Ah,
                                            const int* __restrict__ w,
                                            const float* __restrict__ lut,
                                            _Float16* __restrict__ Bh) {
  __shared__ float slut[256];
  const int bx = blockIdx.x;
  if (bx < 16384) {
    const size_t i = (size_t)bx * 256 + threadIdx.x;
    const float4 x = ((const float4*)in)[2 * i];
    const float4 y = ((const float4*)in)[2 * i + 1];
    half8 h;
    h[0] = (_Float16)x.x; h[1] = (_Float16)x.y; h[2] = (_Float16)x.z; h[3] = (_Float16)x.w;
    h[4] = (_Float16)y.x; h[5] = (_Float16)y.y; h[6] = (_Float16)y.z; h[7] = (_Float16)y.w;
    *(half8*)(Ah + 8 * i) = h;
  } else {
    slut[threadIdx.x] = lut[threadIdx.x];
    __syncthreads();
    const size_t i = (size_t)(bx - 16384) * 256 + threadIdx.x;
    const int4 a = ((const int4*)w)[2 * i];
    const int4 b = ((const int4*)w)[2 * i + 1];
    half8 h;
    h[0] = (_Float16)slut[a.x]; h[1] = (_Float16)slut[a.y];
    h[2] = (_Float16)slut[a.z]; h[3] = (_Float16)slut[a.w];
    h[4] = (_Float16)slut[b.x]; h[5] = (_Float16)slut[b.y];
    h[6] = (_Float16)slut[b.z]; h[7] = (_Float16)slut[b.w];
    *(half8*)(Bh + 8 * i) = h;
  }
}

// ---- C[M][N] = A[M][K] * Bt[N][K]^T + bias ----
// 256x256 tile, BK=64, 8 waves (2Mx4N), per-wave 128x64 out, acc[8][4] f32x4.
__global__ __launch_bounds__(512, 1) void gemm_f16(const _Float16* __restrict__ A,
                                                   const _Float16* __restrict__ Bt,
                                                   const float* __restrict__ bias,
                                                   float* __restrict__ C) {
  __shared__ __align__(16) _Float16 As[2][256 * 64];
  __shared__ __align__(16) _Float16 Bs[2][256 * 64];

  const int tid = threadIdx.x;
  const int lane = tid & 63;
  const int wave = tid >> 6;
  const int wm = wave >> 2;  // 0..1
  const int wn = wave & 3;   // 0..3

  // XCD swizzle: 512 blocks -> 8 chunks of 64 consecutive per XCD.
  const int bid0 = blockIdx.x + blockIdx.y * gridDim.x;  // grid (32,16)
  const int bid = (bid0 & 7) * 64 + (bid0 >> 3);
  const int bm = bid & 31;
  const int bn = bid >> 5;

  // ---- staging: 512 thr x 16B = 64 rows/issuance, 4 per half op.
  // LDS dest linear; swizzle on GLOBAL source chunk: slot (tid&7) gets
  // global chunk (tid&7)^(row&7).
  const int trow = tid >> 3;
  const int tcol = tid & 7;
  const int gch = tcol ^ (trow & 7);
  const _Float16* ag = A + (size_t)(bm * 256 + trow) * Kd + gch * 8;
  const _Float16* bg = Bt + (size_t)(bn * 256 + trow) * Kd + gch * 8;
  const int lds_off = trow * 64 + tcol * 8;

  auto stage = [&](int buf, int kt) {
#pragma unroll
    for (int ht = 0; ht < 4; ++ht) {
      async_copy16(ag + (size_t)kt * 64 + (size_t)ht * (64 * Kd),
                   &As[buf][lds_off + ht * 4096]);
      async_copy16(bg + (size_t)kt * 64 + (size_t)ht * (64 * Kd),
                   &Bs[buf][lds_off + ht * 4096]);
    }
  };

  // ---- fragment addressing: chunk c of row r sits at slot c^(r&7); row=128B.
  // 16x16x32: fr=lane&15 row, fq=lane>>4 selects k-chunk (fq / 4|fq).
  const int fr = lane & 15;
  const int fq = lane >> 4;
  const int e = fr & 7;
  const uint32_t aS0 = (uint32_t)(uintptr_t)&As[0][0] +
                       (uint32_t)((wm * 128 + fr) * 128) + (uint32_t)((fq ^ e) * 16);
  const uint32_t aS1 = (uint32_t)(uintptr_t)&As[0][0] +
                       (uint32_t)((wm * 128 + fr) * 128) + (uint32_t)((((4 | fq) ^ e)) * 16);
  const uint32_t bS0 = (uint32_t)(uintptr_t)&Bs[0][0] +
                       (uint32_t)((wn * 64 + fr) * 128) + (uint32_t)((fq ^ e) * 16);
  const uint32_t bS1 = (uint32_t)(uintptr_t)&Bs[0][0] +
                       (uint32_t)((wn * 64 + fr) * 128) + (uint32_t)((((4 | fq) ^ e)) * 16);
  // buf1 = +32768 bytes, folded into the ds_read offset immediates.

  half8 aL[4][2], aH[4][2], b0[2][2], b1[2][2];
  f32x4 acc[8][4] = {};

  // ---- read groups (single operand sets; entry reuses aL/b0 regs) ----
#define R_AL_0()                                                 \
  R16(aL[0][0], aS0, 0);     R16(aL[0][1], aS1, 0);              \
  R16(aL[1][0], aS0, 2048);  R16(aL[1][1], aS1, 2048);           \
  R16(aL[2][0], aS0, 4096);  R16(aL[2][1], aS1, 4096);           \
  R16(aL[3][0], aS0, 6144);  R16(aL[3][1], aS1, 6144)
#define R_AL_1()                                                 \
  R16(aL[0][0], aS0, 32768); R16(aL[0][1], aS1, 32768);          \
  R16(aL[1][0], aS0, 34816); R16(aL[1][1], aS1, 34816);          \
  R16(aL[2][0], aS0, 36864); R16(aL[2][1], aS1, 36864);          \
  R16(aL[3][0], aS0, 38912); R16(aL[3][1], aS1, 38912)
#define R_B0_0()                                                 \
  R16(b0[0][0], bS0, 0);     R16(b0[0][1], bS1, 0);              \
  R16(b0[1][0], bS0, 2048);  R16(b0[1][1], bS1, 2048)
#define R_B0_1()                                                 \
  R16(b0[0][0], bS0, 32768); R16(b0[0][1], bS1, 32768);          \
  R16(b0[1][0], bS0, 34816); R16(b0[1][1], bS1, 34816)
#define R_B1_0()                                                 \
  R16(b1[0][0], bS0, 4096);  R16(b1[0][1], bS1, 4096);           \
  R16(b1[1][0], bS0, 6144);  R16(b1[1][1], bS1, 6144)
#define R_B1_1()                                                 \
  R16(b1[0][0], bS0, 36864); R16(b1[0][1], bS1, 36864);          \
  R16(b1[1][0], bS0, 38912); R16(b1[1][1], bS1, 38912)
#define R_AH_0()                                                 \
  R16(aH[0][0], aS0, 8192);  R16(aH[0][1], aS1, 8192);           \
  R16(aH[1][0], aS0, 10240); R16(aH[1][1], aS1, 10240);          \
  R16(aH[2][0], aS0, 12288); R16(aH[2][1], aS1, 12288);          \
  R16(aH[3][0], aS0, 14336); R16(aH[3][1], aS1, 14336)
#define R_AH_1()                                                 \
  R16(aH[0][0], aS0, 40960); R16(aH[0][1], aS1, 40960);          \
  R16(aH[1][0], aS0, 43008); R16(aH[1][1], aS1, 43008);          \
  R16(aH[2][0], aS0, 45056); R16(aH[2][1], aS1, 45056);          \
  R16(aH[3][0], aS0, 47104); R16(aH[3][1], aS1, 47104)

#define MF(d, x, y) d = __builtin_amdgcn_mfma_f32_16x16x32_f16(x, y, d, 0, 0, 0)

  // quadrants: P00 acc[i][j] (aL,b0); P01 acc[i][2+j] (aL,b1);
  //            P10 acc[4+i][j] (aH,b0); P11 acc[4+i][2+j] (aH,b1)
#define P00()                                            \
  _Pragma("unroll") for (int i = 0; i < 4; ++i)          \
  _Pragma("unroll") for (int j = 0; j < 2; ++j) {        \
    MF(acc[i][j], aL[i][0], b0[j][0]);                   \
    MF(acc[i][j], aL[i][1], b0[j][1]);                   \
  }
#define P01()                                            \
  _Pragma("unroll") for (int i = 0; i < 4; ++i)          \
  _Pragma("unroll") for (int j = 0; j < 2; ++j) {        \
    MF(acc[i][2 + j], aL[i][0], b1[j][0]);               \
    MF(acc[i][2 + j], aL[i][1], b1[j][1]);               \
  }
#define P10()                                            \
  _Pragma("unroll") for (int i = 0; i < 4; ++i)          \
  _Pragma("unroll") for (int j = 0; j < 2; ++j) {        \
    MF(acc[4 + i][j], aH[i][0], b0[j][0]);               \
    MF(acc[4 + i][j], aH[i][1], b0[j][1]);               \
  }
#define P11A()                                           \
  _Pragma("unroll") for (int i = 0; i < 2; ++i)          \
  _Pragma("unroll") for (int j = 0; j < 2; ++j) {        \
    MF(acc[4 + i][2 + j], aH[i][0], b1[j][0]);           \
    MF(acc[4 + i][2 + j], aH[i][1], b1[j][1]);           \
  }
#define P11B()                                           \
  _Pragma("unroll") for (int i = 2; i < 4; ++i)          \
  _Pragma("unroll") for (int j = 0; j < 2; ++j) {        \
    MF(acc[4 + i][2 + j], aH[i][0], b1[j][0]);           \
    MF(acc[4 + i][2 + j], aH[i][1], b1[j][1]);           \
  }

  // prologue: stage tiles 0,1; wait own tile-0 loads; barrier; entry reads.
  stage(0, 0);
  stage(1, 1);
  VMCNT(8);
  BAR();
  R_AL_0();
  R_B0_0();

  for (int kt = 0; kt < NKT; kt += 2) {
    // ================= even tile kt (buf0) =================
    R_B1_0();                               // 4 reads; outstanding entry12+4
    LGKM(4); SB0(); PRIO1(); P00(); PRIO0();      // entry (aL,b0) drained
    R_AH_0();                               // 8 reads; outstanding 4+8
    LGKM(8); SB0(); PRIO1(); P01(); PRIO0();      // b1 drained
    LGKM(0); SB0(); PRIO1(); P10(); PRIO0();      // aH drained; b0 now dead
    VMCNT(0);  // stage(buf1,kt+1) — issued one full tile ago — complete
    BAR();     // all waves: buf0 read-done + buf1 staged
    // boundary: entry for buf1, interleaved with P11 (aH,b1 in regs)
    R_AL_1();                               // 8 reads into freed aL regs
    SB0(); PRIO1(); P11A(); PRIO0();
    R_B0_1();                               // 4 reads into freed b0 regs
    SB0(); PRIO1(); P11B(); PRIO0();
    if (kt + 2 < NKT) stage(0, kt + 2);     // overwrite buf0 (safe post-BAR)

    // ================= odd tile kt+1 (buf1) ================
    R_B1_1();
    LGKM(4); SB0(); PRIO1(); P00(); PRIO0();
    R_AH_1();
    LGKM(8); SB0(); PRIO1(); P01(); PRIO0();
    LGKM(0); SB0(); PRIO1(); P10(); PRIO0();
    if (kt + 2 < NKT) {
      VMCNT(0);  // stage(buf0,kt+2) — issued after even P11 — complete
      BAR();
      R_AL_0();
      SB0(); PRIO1(); P11A(); PRIO0();
      R_B0_0();
      SB0(); PRIO1(); P11B(); PRIO0();
      stage(1, kt + 3);  // kt+3 <= NKT-1 whenever kt+2 < NKT (NKT even)
    } else {
      SB0(); PRIO1(); P11A(); P11B(); PRIO0();
    }
  }

  // ---- epilogue: C/D layout col = lane&15, row = (lane>>4)*4 + reg
  const int ccol0 = bn * 256 + wn * 64 + fr;
  const int crow0 = bm * 256 + wm * 128 + fq * 4;
  float bv[4];
#pragma unroll
  for (int j = 0; j < 4; ++j) bv[j] = bias[ccol0 + j * 16];
#pragma unroll
  for (int i = 0; i < 8; ++i) {
#pragma unroll
    for (int r = 0; r < 4; ++r) {
      float* cp = C + (size_t)(crow0 + i * 16 + r) * Nd + ccol0;
#pragma unroll
      for (int j = 0; j < 4; ++j) cp[j * 16] = acc[i][j][r] + bv[j];
    }
  }
}

extern "C" void kernel_launch(void* const* d_in, const int* in_sizes, int n_in,
                              void* d_out, int out_size, void* d_ws, size_t ws_size,
                              hipStream_t stream) {
  const float* inp = (const float*)d_in[0];
  const float* lut = (const float*)d_in[1];
  const int* wgt = (const int*)d_in[2];
  const float* bias = (const float*)d_in[3];
  float* out = (float*)d_out;

  _Float16* Ah = (_Float16*)d_ws;
  _Float16* Bh = (_Float16*)d_ws + (size_t)Md * Kd;

  // fused pre-pass: 16384 cvt blocks + 8192 dequant blocks
  prep<<<24576, 256, 0, stream>>>(inp, Ah, wgt, lut, Bh);

  dim3 grid(Md / 256, Nd / 256);  // (32, 16) = 512 blocks
  gemm_f16<<<grid, 512, 0, stream>>>(Ah, Bh, bias, out);
}

// Round 7
// 492.657 us; speedup vs baseline: 2.2999x; 1.4118x over previous
//
#include <hip/hip_runtime.h>
#include <cstdint>

// out[b,s,o] = sum_k in[b,s,k] * lut[w[o,k]] + bias[o]
// GEMM: M=8192, N=4096, K=4096, fp32 out, f16 MFMA path.
//
// R10: gemm = byte-exact R7 restore (verified 242us, MfmaUtil 52.5%, 0
// conflicts, WRITE 135MB). R8/R9 both proved the boundary schedule rides
// ~20 regs from the 256/wave cliff: any reorder that keeps one extra
// operand set live across the boundary spills (R8: 2GB, R9: 430MB scratch).
// Do not touch the loop without disasm.
//
// New this round: prep rewrite. Non-gemm time is ~230-255us across all
// rounds vs an 81us traffic roofline (512MB @ 6.3TB/s). Defects fixed:
//  (a) old pattern loaded v4[2i],v4[2i+1] per thread -> each load insn's
//      lanes touch every OTHER 16B chunk (half-coalesced);
//  (b) 24576 one-shot blocks, no ILP. Now: 2048 blocks grid-stride,
//      4 elems/thread/iter, float4/int4 loads + half4 (8B) stores, all
//      lane-contiguous; 16 (A) + 8 (B) independent iters for latency hiding.
// Predicted: prep ~100-120us, gemm ~242us, total ~380-410us.

static constexpr int Md = 8192;
static constexpr int Nd = 4096;
static constexpr int Kd = 4096;
static constexpr int NKT = Kd / 64;

typedef _Float16 half8 __attribute__((ext_vector_type(8)));
typedef _Float16 half4 __attribute__((ext_vector_type(4)));
typedef float f32x4 __attribute__((ext_vector_type(4)));

__device__ __forceinline__ void async_copy16(const _Float16* g, _Float16* l) {
  __builtin_amdgcn_global_load_lds((const __attribute__((address_space(1))) void*)g,
                                   (__attribute__((address_space(3))) void*)l, 16, 0, 0);
}

#define LGKM(n) asm volatile("s_waitcnt lgkmcnt(" #n ")" ::: "memory")
#define VMCNT(n) asm volatile("s_waitcnt vmcnt(" #n ")" ::: "memory")
#define BAR() __builtin_amdgcn_s_barrier()
#define SB0() __builtin_amdgcn_sched_barrier(0)
#define PRIO1() __builtin_amdgcn_s_setprio(1)
#define PRIO0() __builtin_amdgcn_s_setprio(0)

// ds_read_b128 with literal offset; asm keeps hipcc from inserting vmcnt(0)
// RAW drains against global_load_lds (R5-verified win).
#define R16(dst, base, OFF) \
  asm volatile("ds_read_b128 %0, %1 offset:" #OFF : "=v"(dst) : "v"(base))

// ---- prep: grid-stride, fully coalesced. A: fp32->fp16. B: idx->LUT fp16.
__global__ __launch_bounds__(256) void prep(const float* __restrict__ in,
                                            _Float16* __restrict__ Ah,
                                            const int* __restrict__ w,
                                            const float* __restrict__ lut,
                                            _Float16* __restrict__ Bh) {
  __shared__ float slut[256];
  slut[threadIdx.x] = lut[threadIdx.x];
  __syncthreads();

  const int nthr = gridDim.x * 256;
  const int gid = blockIdx.x * 256 + threadIdx.x;

  const float4* in4 = (const float4*)in;
#pragma unroll 4
  for (size_t i = gid; i < (size_t)Md * Kd / 4; i += nthr) {
    const float4 x = in4[i];
    half4 h;
    h[0] = (_Float16)x.x; h[1] = (_Float16)x.y;
    h[2] = (_Float16)x.z; h[3] = (_Float16)x.w;
    *(half4*)(Ah + 4 * i) = h;
  }

  const int4* w4 = (const int4*)w;
#pragma unroll 4
  for (size_t i = gid; i < (size_t)Nd * Kd / 4; i += nthr) {
    const int4 a = w4[i];
    half4 h;
    h[0] = (_Float16)slut[a.x]; h[1] = (_Float16)slut[a.y];
    h[2] = (_Float16)slut[a.z]; h[3] = (_Float16)slut[a.w];
    *(half4*)(Bh + 4 * i) = h;
  }
}

// ---- C[M][N] = A[M][K] * Bt[N][K]^T + bias ----  (byte-exact R7)
// 256x256 tile, BK=64, 8 waves (2Mx4N), per-wave 128x64 out, acc[8][4] f32x4.
__global__ __launch_bounds__(512, 1) void gemm_f16(const _Float16* __restrict__ A,
                                                   const _Float16* __restrict__ Bt,
                                                   const float* __restrict__ bias,
                                                   float* __restrict__ C) {
  __shared__ __align__(16) _Float16 As[2][256 * 64];
  __shared__ __align__(16) _Float16 Bs[2][256 * 64];

  const int tid = threadIdx.x;
  const int lane = tid & 63;
  const int wave = tid >> 6;
  const int wm = wave >> 2;  // 0..1
  const int wn = wave & 3;   // 0..3

  // XCD swizzle: 512 blocks -> 8 chunks of 64 consecutive per XCD.
  const int bid0 = blockIdx.x + blockIdx.y * gridDim.x;  // grid (32,16)
  const int bid = (bid0 & 7) * 64 + (bid0 >> 3);
  const int bm = bid & 31;
  const int bn = bid >> 5;

  // ---- staging: 512 thr x 16B = 64 rows/issuance, 4 per half op.
  // LDS dest linear; swizzle on GLOBAL source chunk: slot (tid&7) gets
  // global chunk (tid&7)^(row&7).
  const int trow = tid >> 3;
  const int tcol = tid & 7;
  const int gch = tcol ^ (trow & 7);
  const _Float16* ag = A + (size_t)(bm * 256 + trow) * Kd + gch * 8;
  const _Float16* bg = Bt + (size_t)(bn * 256 + trow) * Kd + gch * 8;
  const int lds_off = trow * 64 + tcol * 8;

  auto stage = [&](int buf, int kt) {
#pragma unroll
    for (int ht = 0; ht < 4; ++ht) {
      async_copy16(ag + (size_t)kt * 64 + (size_t)ht * (64 * Kd),
                   &As[buf][lds_off + ht * 4096]);
      async_copy16(bg + (size_t)kt * 64 + (size_t)ht * (64 * Kd),
                   &Bs[buf][lds_off + ht * 4096]);
    }
  };

  // ---- fragment addressing: chunk c of row r sits at slot c^(r&7); row=128B.
  // 16x16x32: fr=lane&15 row, fq=lane>>4 selects k-chunk (fq / 4|fq).
  const int fr = lane & 15;
  const int fq = lane >> 4;
  const int e = fr & 7;
  const uint32_t aS0 = (uint32_t)(uintptr_t)&As[0][0] +
                       (uint32_t)((wm * 128 + fr) * 128) + (uint32_t)((fq ^ e) * 16);
  const uint32_t aS1 = (uint32_t)(uintptr_t)&As[0][0] +
                       (uint32_t)((wm * 128 + fr) * 128) + (uint32_t)((((4 | fq) ^ e)) * 16);
  const uint32_t bS0 = (uint32_t)(uintptr_t)&Bs[0][0] +
                       (uint32_t)((wn * 64 + fr) * 128) + (uint32_t)((fq ^ e) * 16);
  const uint32_t bS1 = (uint32_t)(uintptr_t)&Bs[0][0] +
                       (uint32_t)((wn * 64 + fr) * 128) + (uint32_t)((((4 | fq) ^ e)) * 16);
  // buf1 = +32768 bytes, folded into the ds_read offset immediates.

  half8 aL[4][2], aH[4][2], b0A[2][2], b0B[2][2], b1[2][2];
  f32x4 acc[8][4] = {};

  // 12-read entry set (aL + b0) for each buffer/parity:
#define R_ENTRY_B0()                                             \
  R16(aL[0][0], aS0, 0);     R16(aL[0][1], aS1, 0);              \
  R16(aL[1][0], aS0, 2048);  R16(aL[1][1], aS1, 2048);           \
  R16(aL[2][0], aS0, 4096);  R16(aL[2][1], aS1, 4096);           \
  R16(aL[3][0], aS0, 6144);  R16(aL[3][1], aS1, 6144);           \
  R16(b0A[0][0], bS0, 0);    R16(b0A[0][1], bS1, 0);             \
  R16(b0A[1][0], bS0, 2048); R16(b0A[1][1], bS1, 2048)

#define R_ENTRY_B1()                                             \
  R16(aL[0][0], aS0, 32768); R16(aL[0][1], aS1, 32768);          \
  R16(aL[1][0], aS0, 34816); R16(aL[1][1], aS1, 34816);          \
  R16(aL[2][0], aS0, 36864); R16(aL[2][1], aS1, 36864);          \
  R16(aL[3][0], aS0, 38912); R16(aL[3][1], aS1, 38912);          \
  R16(b0B[0][0], bS0, 32768); R16(b0B[0][1], bS1, 32768);        \
  R16(b0B[1][0], bS0, 34816); R16(b0B[1][1], bS1, 34816)

#define R_B1_0()                                                 \
  R16(b1[0][0], bS0, 4096);  R16(b1[0][1], bS1, 4096);           \
  R16(b1[1][0], bS0, 6144);  R16(b1[1][1], bS1, 6144)

#define R_B1_1()                                                 \
  R16(b1[0][0], bS0, 36864); R16(b1[0][1], bS1, 36864);          \
  R16(b1[1][0], bS0, 38912); R16(b1[1][1], bS1, 38912)

#define R_AH_0()                                                 \
  R16(aH[0][0], aS0, 8192);  R16(aH[0][1], aS1, 8192);           \
  R16(aH[1][0], aS0, 10240); R16(aH[1][1], aS1, 10240);          \
  R16(aH[2][0], aS0, 12288); R16(aH[2][1], aS1, 12288);          \
  R16(aH[3][0], aS0, 14336); R16(aH[3][1], aS1, 14336)

#define R_AH_1()                                                 \
  R16(aH[0][0], aS0, 40960); R16(aH[0][1], aS1, 40960);          \
  R16(aH[1][0], aS0, 43008); R16(aH[1][1], aS1, 43008);          \
  R16(aH[2][0], aS0, 45056); R16(aH[2][1], aS1, 45056);          \
  R16(aH[3][0], aS0, 47104); R16(aH[3][1], aS1, 47104)

#define MF(d, x, y) d = __builtin_amdgcn_mfma_f32_16x16x32_f16(x, y, d, 0, 0, 0)

#define PH0(B0)                                          \
  _Pragma("unroll") for (int i = 0; i < 4; ++i)          \
  _Pragma("unroll") for (int j = 0; j < 2; ++j) {        \
    MF(acc[i][j], aL[i][0], B0[j][0]);                   \
    MF(acc[i][j], aL[i][1], B0[j][1]);                   \
  }
#define PH1()                                            \
  _Pragma("unroll") for (int i = 0; i < 4; ++i)          \
  _Pragma("unroll") for (int j = 0; j < 2; ++j) {        \
    MF(acc[i][2 + j], aL[i][0], b1[j][0]);               \
    MF(acc[i][2 + j], aL[i][1], b1[j][1]);               \
  }
#define PH2()                                            \
  _Pragma("unroll") for (int i = 0; i < 4; ++i)          \
  _Pragma("unroll") for (int j = 0; j < 2; ++j) {        \
    MF(acc[4 + i][2 + j], aH[i][0], b1[j][0]);           \
    MF(acc[4 + i][2 + j], aH[i][1], b1[j][1]);           \
  }
#define PH3(B0)                                          \
  _Pragma("unroll") for (int i = 0; i < 4; ++i)          \
  _Pragma("unroll") for (int j = 0; j < 2; ++j) {        \
    MF(acc[4 + i][j], aH[i][0], B0[j][0]);               \
    MF(acc[4 + i][j], aH[i][1], B0[j][1]);               \
  }

  // prologue: stage tiles 0,1; wait own tile-0 loads; barrier; entry reads.
  stage(0, 0);
  stage(1, 1);
  VMCNT(8);
  BAR();
  R_ENTRY_B0();

  for (int kt = 0; kt < NKT; kt += 2) {
    // ================= even tile kt (buf0, parity A) =================
    R_B1_0();                               // 4 reads; outstanding 12+4
    LGKM(4); SB0(); PRIO1(); PH0(b0A); PRIO0();   // entry reads drained
    R_AH_0();                               // 8 reads; outstanding 4+8
    LGKM(8); SB0(); PRIO1(); PH1(); PRIO0();      // b1 drained
    LGKM(0); SB0(); PRIO1(); PH2(); PRIO0();      // aH drained
    VMCNT(0);  // stage(buf1, kt+1) — issued one full tile ago
    BAR();     // buf1 ready for reads; all waves done reading buf0
    R_ENTRY_B1();                           // 12 reads for tile kt+1
    if (kt + 2 < NKT) stage(0, kt + 2);     // overwrite buf0 (safe post-BAR)
    SB0(); PRIO1(); PH3(b0A); PRIO0();      // operands already in regs

    // ================= odd tile kt+1 (buf1, parity B) ================
    R_B1_1();
    LGKM(4); SB0(); PRIO1(); PH0(b0B); PRIO0();
    R_AH_1();
    LGKM(8); SB0(); PRIO1(); PH1(); PRIO0();
    LGKM(0); SB0(); PRIO1(); PH2(); PRIO0();
    VMCNT(0);  // stage(buf0, kt+2) — issued above, one tile ago
    BAR();
    if (kt + 2 < NKT) {
      R_ENTRY_B0();                         // 12 reads for tile kt+2
      if (kt + 3 < NKT) stage(1, kt + 3);
    }
    SB0(); PRIO1(); PH3(b0B); PRIO0();
  }

  // ---- epilogue: C/D layout col = lane&15, row = (lane>>4)*4 + reg
  const int ccol0 = bn * 256 + wn * 64 + fr;
  const int crow0 = bm * 256 + wm * 128 + fq * 4;
  float bv[4];
#pragma unroll
  for (int j = 0; j < 4; ++j) bv[j] = bias[ccol0 + j * 16];
#pragma unroll
  for (int i = 0; i < 8; ++i) {
#pragma unroll
    for (int r = 0; r < 4; ++r) {
      float* cp = C + (size_t)(crow0 + i * 16 + r) * Nd + ccol0;
#pragma unroll
      for (int j = 0; j < 4; ++j) cp[j * 16] = acc[i][j][r] + bv[j];
    }
  }
}

extern "C" void kernel_launch(void* const* d_in, const int* in_sizes, int n_in,
                              void* d_out, int out_size, void* d_ws, size_t ws_size,
                              hipStream_t stream) {
  const float* inp = (const float*)d_in[0];
  const float* lut = (const float*)d_in[1];
  const int* wgt = (const int*)d_in[2];
  const float* bias = (const float*)d_in[3];
  float* out = (float*)d_out;

  _Float16* Ah = (_Float16*)d_ws;
  _Float16* Bh = (_Float16*)d_ws + (size_t)Md * Kd;

  // grid-stride coalesced pre-pass
  prep<<<2048, 256, 0, stream>>>(inp, Ah, wgt, lut, Bh);

  dim3 grid(Md / 256, Nd / 256);  // (32, 16) = 512 blocks
  gemm_f16<<<grid, 512, 0, stream>>>(Ah, Bh, bias, out);
}